// Round 7
// baseline (356.459 us; speedup 1.0000x reference)
//
#include <hip/hip_runtime.h>

#define B_    128
#define NELEC 192
#define NAO   128
#define NMO   96
#define NCONF 32
#define L_    80

__global__ void zero_out_k(float* out) { if (threadIdx.x < B_) out[threadIdx.x] = 0.f; }

// G[b][s][m] = sum_n ao[b][2s][n] * mo_w[m][n]; blocks with st==0 also zero out[b]
__global__ __launch_bounds__(256) void gemm_g_k(const float* __restrict__ ao,
                                                const float* __restrict__ mo_w,
                                                float* __restrict__ G,
                                                float* __restrict__ out) {
    int b  = blockIdx.x;
    int st = blockIdx.y;
    int tid = threadIdx.x;
    if (st == 0 && tid == 0) out[b] = 0.f;
    int s_local = tid >> 4;
    int m0 = (tid & 15) * 6;
    int s = st * 16 + s_local;
    const float* arow = ao + ((size_t)b * NELEC + 2 * s) * NAO;
    const float* w0   = mo_w + (size_t)m0 * NAO;
    float acc[6] = {0.f, 0.f, 0.f, 0.f, 0.f, 0.f};
    for (int n = 0; n < NAO; n += 4) {
        float4 av = *(const float4*)(arow + n);
#pragma unroll
        for (int q = 0; q < 6; ++q) {
            float4 wv = *(const float4*)(w0 + (size_t)q * NAO + n);
            acc[q] += av.x * wv.x + av.y * wv.y + av.z * wv.z + av.w * wv.w;
        }
    }
    float* grow = G + ((size_t)b * NMO + s) * NMO + m0;
#pragma unroll
    for (int q = 0; q < 6; ++q) grow[q] = acc[q];
}

__device__ __forceinline__ float rdlane(float x, int src) {
    return __int_as_float(__builtin_amdgcn_readlane(__float_as_int(x), src));
}
__device__ __forceinline__ int rdlanei(int x, int src) {
    return __builtin_amdgcn_readlane(x, src);
}
#define DPPMAX(v, ctrl)                                                          \
    v = fmaxf(v, __int_as_float(__builtin_amdgcn_update_dpp(                     \
            __float_as_int(v), __float_as_int(v), (ctrl), 0xf, 0xf, false)))

// u-source for guardian rows: col k+X of pivot row = a[X] (X<64) or T[p][X-64].
// X is a compile-time constant after unroll; indices clamped so dead arm stays in-bounds.
#define USRC(X) (((X) < 64) ? rdlane(a[((X) < 64) ? (X) : 0], p)                 \
                            : T[p * 17 + (((X) >= 64) ? ((X) - 64) : 0)])

// One WAVE per (config c, batch b).
// Register row is EXACTLY 64 floats/lane (round-6 showed 81 floats/lane forces
// AGPR overflow: VGPR=96 + ~160 AGPR, occupancy 2 waves/SIMD, accvgpr traffic).
// Cols 64..79 of each reg row live in LDS tails T[64][17] (stride 17 -> 2-way
// bank = free). Rows 64..79 are full LDS rows (Ms[23..38]), guardian-updated.
// Phase 1 (k<16): pivot among 64 reg rows; 63 static reg FMAs + boundary from
// T; tail shifts in LDS (pivot lane retired -> never writes -> race-free in a
// single wave). Compaction at k=16, then pure-register phase 2 (as round 6).
template <bool USE_G>
__global__ __launch_bounds__(64) void det_reg_k(const float* __restrict__ ao,
                                                const float* __restrict__ mo_w,
                                                const float* __restrict__ G,
                                                const float* __restrict__ ci_w,
                                                const int* __restrict__ conf_idx,
                                                float* __restrict__ out) {
    __shared__ __align__(16) float Ms[40][84];   // staging: rows 13..39; rows 23..38 persist as B rows 64..79
    __shared__ int sIdx[L_];
    __shared__ int tbl[64];
    float* T = &Ms[0][0];                        // tails: 64*17=1088 floats, overlays Ms rows 0..12 (1092)

    int c = blockIdx.x;   // 32
    int b = blockIdx.y;   // 128
    int lane = threadIdx.x;

    if (lane < 64) sIdx[lane] = conf_idx[c * L_ + lane] >> 1;
    if (lane < 16) sIdx[64 + lane] = conf_idx[c * L_ + 64 + lane] >> 1;
    __syncthreads();

    float a[64];
    float4 tl0, tl1, tl2, tl3;
    const float* Gb = G + (size_t)b * NMO * NMO;

    // ---- 3-pass staging: rows [0..26],[27..53],[54..79] into Ms[13..39].
    //      Reg rows 0..63 read out to a[]+tail regs; tails written to T after
    //      the row region is consumed; rows 64..79 (pass 3, Ms[23..38]) persist.
#pragma unroll 1
    for (int pass = 0; pass < 3; ++pass) {
        int r0 = pass * 27;
        int nrows = (pass == 2) ? 26 : 27;
        for (int e = lane; e < nrows * L_; e += 64) {
            int i = e / L_, j = e - i * L_;
            float v;
            if (USE_G) {
                v = Gb[(size_t)sIdx[r0 + i] * NMO + sIdx[j]];
            } else {
                const float* ar = ao + ((size_t)b * NELEC + 2 * sIdx[r0 + i]) * NAO;
                const float* wr = mo_w + (size_t)sIdx[j] * NAO;
                float acc = 0.f;
                for (int n = 0; n < NAO; n += 4) {
                    float4 av = *(const float4*)(ar + n);
                    float4 wv = *(const float4*)(wr + n);
                    acc += av.x * wv.x + av.y * wv.y + av.z * wv.z + av.w * wv.w;
                }
                v = acc;
            }
            Ms[13 + i][j] = v;
        }
        __syncthreads();
        bool mine = (lane >= r0) && (lane < r0 + nrows) && (lane < 64);
        if (mine) {
            const float* R = &Ms[13 + (lane - r0)][0];
#pragma unroll
            for (int q = 0; q < 16; ++q) {
                float4 v4 = *(const float4*)&R[4 * q];
                a[4 * q] = v4.x; a[4 * q + 1] = v4.y; a[4 * q + 2] = v4.z; a[4 * q + 3] = v4.w;
            }
            tl0 = *(const float4*)&R[64]; tl1 = *(const float4*)&R[68];
            tl2 = *(const float4*)&R[72]; tl3 = *(const float4*)&R[76];
        }
        __syncthreads();
        if (mine) {
            float* Tr = &T[lane * 17];
            Tr[0]  = tl0.x; Tr[1]  = tl0.y; Tr[2]  = tl0.z; Tr[3]  = tl0.w;
            Tr[4]  = tl1.x; Tr[5]  = tl1.y; Tr[6]  = tl1.z; Tr[7]  = tl1.w;
            Tr[8]  = tl2.x; Tr[9]  = tl2.y; Tr[10] = tl2.z; Tr[11] = tl2.w;
            Tr[12] = tl3.x; Tr[13] = tl3.y; Tr[14] = tl3.z; Tr[15] = tl3.w;
        }
        __syncthreads();
    }

    double det = 1.0;
    int inv = 0;
    bool act = true;

    // ---------------- phase 1: k = 0..15 (row width 80-k >= 65) ----------------
#pragma unroll 1
    for (int k = 0; k < 16; ++k) {
        float cand = act ? fabsf(a[0]) : -1.f;
        float m = cand;
        DPPMAX(m, 0x111); DPPMAX(m, 0x112); DPPMAX(m, 0x114); DPPMAX(m, 0x118);
        DPPMAX(m, 0x142); DPPMAX(m, 0x143);
        float mx = rdlane(m, 63);
        unsigned long long sel = __ballot(act && cand == mx);
        int p = __ffsll(sel) - 1;
        inv += __popcll(__ballot(act && lane < p));
        float piv = rdlane(a[0], p);
        det *= (double)piv;
        if (lane == p) act = false;
        float la = (act && piv != 0.f) ? a[0] / piv : 0.f;
        int w = 16 - k;        // current tail width
        int rem = 79 - k;      // new row width

        // ---- guardian update of full LDS rows 64..79 (uses OLD a[], OLD T[p])
        if (lane < 16) {
            float* Brow = &Ms[23 + lane][0];
            float4 Qc = *(const float4*)&Brow[0];
            float lb = (piv != 0.f) ? Qc.x / piv : 0.f;
#pragma unroll
            for (int tb = 0; tb < 5; ++tb) {
                if (16 * tb < rem) {
#pragma unroll
                    for (int j = 0; j < 4; ++j) {
                        float4 Qn = *(const float4*)&Brow[16 * tb + 4 * j + 4];
                        float4 W;
                        W.x = fmaf(-lb, USRC(16 * tb + 4 * j + 1), Qc.y);
                        W.y = fmaf(-lb, USRC(16 * tb + 4 * j + 2), Qc.z);
                        W.z = fmaf(-lb, USRC(16 * tb + 4 * j + 3), Qc.w);
                        W.w = fmaf(-lb, USRC(16 * tb + 4 * j + 4), Qn.x);
                        *(float4*)&Brow[16 * tb + 4 * j] = W;
                        Qc = Qn;
                    }
                }
            }
        }

        // ---- main reg shift: 63 static FMAs + boundary from tail (old T)
        float myT0 = T[lane * 17];
        float uT0  = T[p * 17];
#pragma unroll
        for (int tb = 0; tb < 4; ++tb) {
#pragma unroll
            for (int i = 0; i < 16; ++i) {
                int t = 16 * tb + i;
                if (t < 63) {
                    float u = rdlane(a[t + 1], p);
                    a[t] = fmaf(-la, u, a[t + 1]);
                }
            }
        }
        a[63] = fmaf(-la, uT0, myT0);

        // ---- tail shift in LDS (active lanes only; lane p retired -> T[p] frozen)
        if (act) {
            float* Tr = &T[lane * 17];
#pragma unroll
            for (int j = 0; j < 15; ++j) {
                if (j < w - 1) {
                    float tn = Tr[j + 1];
                    float un = T[p * 17 + j + 1];
                    Tr[j] = fmaf(-la, un, tn);
                }
            }
        }
    }

    // ---------------- compaction: 48 reg + 16 LDS actives -> 1 row/lane ----------------
    unsigned long long mask_a = __ballot(act);
    int rank = __popcll(mask_a & ((1ull << lane) - 1));
    if (act) tbl[rank] = lane;
    __syncthreads();
    int srcl = tbl[lane & 63];                 // valid for lane<48
    int src2 = (lane < 48) ? srcl : lane;
#pragma unroll
    for (int t = 0; t < 64; ++t) a[t] = __shfl(a[t], src2);
    if (lane >= 48) {
        const float* Brow = &Ms[23 + (lane - 48)][0];
#pragma unroll
        for (int q = 0; q < 16; ++q) {
            float4 v4 = *(const float4*)&Brow[4 * q];
            a[4 * q] = v4.x; a[4 * q + 1] = v4.y; a[4 * q + 2] = v4.z; a[4 * q + 3] = v4.w;
        }
    }
    int rowid = (lane < 48) ? srcl : (16 + lane);   // 64 + (lane-48)
    act = true;

    // ---------------- phase 2: k = 16..79 (pure registers, width <= 64) ----------------
#pragma unroll 1
    for (int k = 16; k < 80; ++k) {
        int rem = 79 - k;
        float cand = act ? fabsf(a[0]) : -1.f;
        float m = cand;
        DPPMAX(m, 0x111); DPPMAX(m, 0x112); DPPMAX(m, 0x114); DPPMAX(m, 0x118);
        DPPMAX(m, 0x142); DPPMAX(m, 0x143);
        float mx = rdlane(m, 63);
        unsigned long long sel = __ballot(act && cand == mx);
        int p = __ffsll(sel) - 1;

        int pr = rdlanei(rowid, p);
        inv += __popcll(__ballot(act && rowid < pr));

        float piv = rdlane(a[0], p);
        det *= (double)piv;
        if (lane == p) act = false;
        float la = (act && piv != 0.f) ? a[0] / piv : 0.f;

#pragma unroll
        for (int tb = 0; tb < 4; ++tb) {
            if (16 * tb < rem) {
#pragma unroll
                for (int i = 0; i < 16; ++i) {
                    int t = 16 * tb + i;
                    if (t < 63) {          // static trim: never touch a[64]
                        float u = rdlane(a[t + 1], p);
                        a[t] = fmaf(-la, u, a[t + 1]);
                    }
                }
            }
        }
    }

    if (lane == 0) {
        double sgn = (inv & 1) ? -1.0 : 1.0;
        atomicAdd(&out[b], (float)(det * sgn * (double)ci_w[c]));
    }
}

extern "C" void kernel_launch(void* const* d_in, const int* in_sizes, int n_in,
                              void* d_out, int out_size, void* d_ws, size_t ws_size,
                              hipStream_t stream) {
    const float* ao    = (const float*)d_in[0];   // (128,192,128) f32
    const float* mo_w  = (const float*)d_in[1];   // (96,128) f32
    const float* ci_w  = (const float*)d_in[2];   // (1,32) f32
    const int*   conf  = (const int*)d_in[3];     // (32,80) i32
    float* out = (float*)d_out;                   // (128,1) f32
    float* G   = (float*)d_ws;

    const size_t g_need = (size_t)B_ * NMO * NMO * sizeof(float);  // 4.72 MB
    if (ws_size >= g_need) {
        gemm_g_k<<<dim3(B_, 6), dim3(256), 0, stream>>>(ao, mo_w, G, out);
        det_reg_k<true><<<dim3(NCONF, B_), dim3(64), 0, stream>>>(ao, mo_w, G, ci_w, conf, out);
    } else {
        zero_out_k<<<dim3(1), dim3(B_), 0, stream>>>(out);
        det_reg_k<false><<<dim3(NCONF, B_), dim3(64), 0, stream>>>(ao, mo_w, nullptr, ci_w, conf, out);
    }
}

// Round 8
// 319.772 us; speedup vs baseline: 1.1147x; 1.1147x over previous
//
#include <hip/hip_runtime.h>

#define B_    128
#define NELEC 192
#define NAO   128
#define NMO   96
#define NCONF 32
#define L_    80

__global__ void zero_out_k(float* out) { if (threadIdx.x < B_) out[threadIdx.x] = 0.f; }

// G[b][s][m] = sum_n ao[b][2s][n] * mo_w[m][n]; blocks with st==0 also zero out[b]
__global__ __launch_bounds__(256) void gemm_g_k(const float* __restrict__ ao,
                                                const float* __restrict__ mo_w,
                                                float* __restrict__ G,
                                                float* __restrict__ out) {
    int b  = blockIdx.x;
    int st = blockIdx.y;
    int tid = threadIdx.x;
    if (st == 0 && tid == 0) out[b] = 0.f;
    int s_local = tid >> 4;
    int m0 = (tid & 15) * 6;
    int s = st * 16 + s_local;
    const float* arow = ao + ((size_t)b * NELEC + 2 * s) * NAO;
    const float* w0   = mo_w + (size_t)m0 * NAO;
    float acc[6] = {0.f, 0.f, 0.f, 0.f, 0.f, 0.f};
    for (int n = 0; n < NAO; n += 4) {
        float4 av = *(const float4*)(arow + n);
#pragma unroll
        for (int q = 0; q < 6; ++q) {
            float4 wv = *(const float4*)(w0 + (size_t)q * NAO + n);
            acc[q] += av.x * wv.x + av.y * wv.y + av.z * wv.z + av.w * wv.w;
        }
    }
    float* grow = G + ((size_t)b * NMO + s) * NMO + m0;
#pragma unroll
    for (int q = 0; q < 6; ++q) grow[q] = acc[q];
}

__device__ __forceinline__ float rdlane(float x, int src) {
    return __int_as_float(__builtin_amdgcn_readlane(__float_as_int(x), src));
}
__device__ __forceinline__ int rdlanei(int x, int src) {
    return __builtin_amdgcn_readlane(x, src);
}
// one stage of a DPP max-reduce (VALU pipe, not LDS)
#define DPPMAX(v, ctrl)                                                          \
    v = fmaxf(v, __int_as_float(__builtin_amdgcn_update_dpp(                     \
            __float_as_int(v), __float_as_int(v), (ctrl), 0xf, 0xf, false)))

// One WAVE per (config c, batch b). Round-6 structure (a[81] register rows,
// 16 LDS guardian rows in phase 1, compaction, pure-reg phase 2).
//
// KEY FIX (rounds 3/6/7 post-mortem): with no waves-per-eu pin, LLVM's
// occupancy heuristic caps arch VGPRs (172/96/68 across rounds) and parks
// the row array in AGPRs; real occupancy collapses to 1-2 waves/SIMD anyway
// and every touch pays v_accvgpr_read/write. amdgpu_waves_per_eu(2,2) pins
// the target: budget 256 regs/wave >> demand (~140), so the array stays in
// arch VGPRs. (Round 5 showed min-only bounds BELOW demand cause full
// scratch spill - here the budget is far above demand.)
template <bool USE_G>
__global__ __launch_bounds__(64)
__attribute__((amdgpu_waves_per_eu(2, 2)))
void det_reg_k(const float* __restrict__ ao,
               const float* __restrict__ mo_w,
               const float* __restrict__ G,
               const float* __restrict__ ci_w,
               const int* __restrict__ conf_idx,
               float* __restrict__ out) {
    __shared__ __align__(16) float Ms[40][84];   // staging; rows 24..39 persist as B rows 64..79
    __shared__ int sIdx[L_];
    __shared__ int tbl[64];

    int c = blockIdx.x;   // 32
    int b = blockIdx.y;   // 128
    int lane = threadIdx.x;

    if (lane < 64) sIdx[lane] = conf_idx[c * L_ + lane] >> 1;
    if (lane < 16) sIdx[64 + lane] = conf_idx[c * L_ + 64 + lane] >> 1;
    __syncthreads();

    float a[81];
#pragma unroll
    for (int t = 0; t < 81; ++t) a[t] = 0.f;

    const float* Gb = G + (size_t)b * NMO * NMO;

    // ---- gather: pass 0 stages rows 0..39 (readout lanes 0..39);
    //      pass 1 stages rows 40..79 (readout lanes 40..63; Ms[24..39] = LDS rows 64..79)
#pragma unroll 1
    for (int pass = 0; pass < 2; ++pass) {
        int r0 = pass * 40;
        for (int e = lane; e < 40 * L_; e += 64) {
            int i = e / L_, j = e - i * L_;
            float v;
            if (USE_G) {
                v = Gb[(size_t)sIdx[r0 + i] * NMO + sIdx[j]];
            } else {
                const float* ar = ao + ((size_t)b * NELEC + 2 * sIdx[r0 + i]) * NAO;
                const float* wr = mo_w + (size_t)sIdx[j] * NAO;
                float acc = 0.f;
                for (int n = 0; n < NAO; n += 4) {
                    float4 av = *(const float4*)(ar + n);
                    float4 wv = *(const float4*)(wr + n);
                    acc += av.x * wv.x + av.y * wv.y + av.z * wv.z + av.w * wv.w;
                }
                v = acc;
            }
            Ms[i][j] = v;
        }
        __syncthreads();
        if (pass == 0) {
            if (lane < 40) {
#pragma unroll
                for (int q = 0; q < 20; ++q) {
                    float4 v4 = *(const float4*)&Ms[lane][4 * q];
                    a[4 * q] = v4.x; a[4 * q + 1] = v4.y; a[4 * q + 2] = v4.z; a[4 * q + 3] = v4.w;
                }
            }
        } else {
            if (lane >= 40) {
#pragma unroll
                for (int q = 0; q < 20; ++q) {
                    float4 v4 = *(const float4*)&Ms[lane - 40][4 * q];
                    a[4 * q] = v4.x; a[4 * q + 1] = v4.y; a[4 * q + 2] = v4.z; a[4 * q + 3] = v4.w;
                }
            }
        }
        __syncthreads();
    }

    double det = 1.0;
    int inv = 0;
    bool act = true;      // reg row active
    // phase-1 reg rowid == lane; LDS-row ids 64..79 (never pivots, never < pr)

    // ---------------- phase 1: k = 0..15 ----------------
#pragma unroll 1
    for (int k = 0; k < 16; ++k) {
        int rem = 79 - k;
        float cand = act ? fabsf(a[0]) : -1.f;
        float m = cand;
        DPPMAX(m, 0x111); DPPMAX(m, 0x112); DPPMAX(m, 0x114); DPPMAX(m, 0x118);
        DPPMAX(m, 0x142); DPPMAX(m, 0x143);
        float mx = rdlane(m, 63);
        unsigned long long sel = __ballot(act && cand == mx);
        int p = __ffsll(sel) - 1;

        inv += __popcll(__ballot(act && lane < p));

        float piv = rdlane(a[0], p);
        det *= (double)piv;
        if (lane == p) act = false;
        float la = (act && piv != 0.f) ? a[0] / piv : 0.f;

        // ---- LDS B-row shift-update (guardians, quad window; all idx static)
        if (lane < 16) {
            float* Brow = &Ms[24 + lane][0];
            float4 Qc = *(const float4*)&Brow[0];
            float lb = (piv != 0.f) ? Qc.x / piv : 0.f;
#pragma unroll
            for (int tb = 0; tb < 5; ++tb) {
                if (16 * tb < rem) {
#pragma unroll
                    for (int j = 0; j < 4; ++j) {
                        float4 Qn = *(const float4*)&Brow[16 * tb + 4 * j + 4];
                        float4 W;
                        W.x = fmaf(-lb, rdlane(a[16 * tb + 4 * j + 1], p), Qc.y);
                        W.y = fmaf(-lb, rdlane(a[16 * tb + 4 * j + 2], p), Qc.z);
                        W.z = fmaf(-lb, rdlane(a[16 * tb + 4 * j + 3], p), Qc.w);
                        W.w = fmaf(-lb, rdlane(a[16 * tb + 4 * j + 4], p), Qn.x);
                        *(float4*)&Brow[16 * tb + 4 * j] = W;
                        Qc = Qn;
                    }
                }
            }
        }

        // ---- register row shift-update (reads a[t+1] before it's overwritten)
#pragma unroll
        for (int tb = 0; tb < 5; ++tb) {
            if (16 * tb < rem) {
#pragma unroll
                for (int i = 0; i < 16; ++i) {
                    float u = rdlane(a[16 * tb + i + 1], p);
                    a[16 * tb + i] = fmaf(-la, u, a[16 * tb + i + 1]);
                }
            }
        }
    }

    // ---------------- compaction: 48 reg + 16 LDS actives -> 1 row/lane ----------------
    unsigned long long mask_a = __ballot(act);
    int rank = __popcll(mask_a & ((1ull << lane) - 1));
    if (act) tbl[rank] = lane;
    __syncthreads();
    int srcl = tbl[lane & 63];                 // valid for lane<48
    int src2 = (lane < 48) ? srcl : lane;
#pragma unroll
    for (int t = 0; t < 64; ++t) a[t] = __shfl(a[t], src2);
    if (lane >= 48) {
        const float* Brow = &Ms[24 + (lane - 48)][0];
#pragma unroll
        for (int q = 0; q < 16; ++q) {
            float4 v4 = *(const float4*)&Brow[4 * q];
            a[4 * q] = v4.x; a[4 * q + 1] = v4.y; a[4 * q + 2] = v4.z; a[4 * q + 3] = v4.w;
        }
    }
    int rowid = (lane < 48) ? srcl : (16 + lane);   // 64 + (lane-48)
    act = true;

    // ---------------- phase 2: k = 16..79 ----------------
#pragma unroll 1
    for (int k = 16; k < 80; ++k) {
        int rem = 79 - k;
        float cand = act ? fabsf(a[0]) : -1.f;
        float m = cand;
        DPPMAX(m, 0x111); DPPMAX(m, 0x112); DPPMAX(m, 0x114); DPPMAX(m, 0x118);
        DPPMAX(m, 0x142); DPPMAX(m, 0x143);
        float mx = rdlane(m, 63);
        unsigned long long sel = __ballot(act && cand == mx);
        int p = __ffsll(sel) - 1;

        int pr = rdlanei(rowid, p);
        inv += __popcll(__ballot(act && rowid < pr));

        float piv = rdlane(a[0], p);
        det *= (double)piv;
        if (lane == p) act = false;
        float la = (act && piv != 0.f) ? a[0] / piv : 0.f;

#pragma unroll
        for (int tb = 0; tb < 4; ++tb) {
            if (16 * tb < rem) {
#pragma unroll
                for (int i = 0; i < 16; ++i) {
                    float u = rdlane(a[16 * tb + i + 1], p);
                    a[16 * tb + i] = fmaf(-la, u, a[16 * tb + i + 1]);
                }
            }
        }
    }

    if (lane == 0) {
        double sgn = (inv & 1) ? -1.0 : 1.0;
        atomicAdd(&out[b], (float)(det * sgn * (double)ci_w[c]));
    }
}

extern "C" void kernel_launch(void* const* d_in, const int* in_sizes, int n_in,
                              void* d_out, int out_size, void* d_ws, size_t ws_size,
                              hipStream_t stream) {
    const float* ao    = (const float*)d_in[0];   // (128,192,128) f32
    const float* mo_w  = (const float*)d_in[1];   // (96,128) f32
    const float* ci_w  = (const float*)d_in[2];   // (1,32) f32
    const int*   conf  = (const int*)d_in[3];     // (32,80) i32
    float* out = (float*)d_out;                   // (128,1) f32
    float* G   = (float*)d_ws;

    const size_t g_need = (size_t)B_ * NMO * NMO * sizeof(float);  // 4.72 MB
    if (ws_size >= g_need) {
        gemm_g_k<<<dim3(B_, 6), dim3(256), 0, stream>>>(ao, mo_w, G, out);
        det_reg_k<true><<<dim3(NCONF, B_), dim3(64), 0, stream>>>(ao, mo_w, G, ci_w, conf, out);
    } else {
        zero_out_k<<<dim3(1), dim3(B_), 0, stream>>>(out);
        det_reg_k<false><<<dim3(NCONF, B_), dim3(64), 0, stream>>>(ao, mo_w, nullptr, ci_w, conf, out);
    }
}